// Round 3
// baseline (96.189 us; speedup 1.0000x reference)
//
#include <hip/hip_runtime.h>

#define EPS_F 1e-6f
#define LOG2E 1.4426950408889634f

// 4-byte-aligned vector loads (feat rows are 60 B apart -> not 16 B aligned;
// gfx950 global_load_dwordx4/x3 only need dword alignment).
typedef float f4 __attribute__((ext_vector_type(4), aligned(4)));
typedef float f3 __attribute__((ext_vector_type(3), aligned(4)));

// Force a (known-uniform) float into an SGPR.
__device__ __forceinline__ float rfl(float x) {
    return __builtin_bit_cast(float, __builtin_amdgcn_readfirstlane(__builtin_bit_cast(int, x)));
}

// Block: 256 threads = 8 m (mi = tid>>5) x 32 n-splits (ns = tid&31).
// Grid: 2048 blocks = B(8) x 128 m-tiles x 2 n-halves -> 8 blocks/CU.
// Each thread sums 16 interleaved n's (n = half*512 + i*32 + ns), partials
// combined in LDS, one plain store per output element. No atomics.
__global__ __launch_bounds__(256, 8) void icgp_rbf_kernel(
    const float* __restrict__ xa,       // (B, N1, 1, 3)
    const float* __restrict__ feat,     // (B, N1, 5, 3)
    const float* __restrict__ xt,       // (B, N2, 1, 3)
    const float* __restrict__ log_std,  // (1, 5, 3)
    float* __restrict__ out)            // (B, N2, 5, 3)
{
    __shared__ float lds[256 * 15];     // 15 KB partials

    const int bid = blockIdx.x;
    const int nh  = bid & 1;            // n-half
    const int mt  = (bid >> 1) & 127;   // m-tile (8 m's)
    const int b   = bid >> 8;
    const int tid = threadIdx.x;
    const int mi  = tid >> 5;           // 0..7
    const int ns  = tid & 31;           // 0..31
    const int m   = mt * 8 + mi;

    // wt = exp2(coef * (xa-xt)^2), coef = -0.5*log2(e)/std^2 ; wave-uniform -> SGPR.
    float coef[15];
    #pragma unroll
    for (int kc = 0; kc < 15; ++kc) {
        float s = __expf(log_std[kc]) + EPS_F;
        coef[kc] = rfl(-0.5f * LOG2E / (s * s));
    }

    // Runtime check: all K coefficients identical per channel? (true for given params)
    bool uni = true;
    #pragma unroll
    for (int k = 1; k < 5; ++k)
        #pragma unroll
        for (int c = 0; c < 3; ++c)
            uni = uni && (coef[k * 3 + c] == coef[c]);

    const float t0 = xt[(b * 1024 + m) * 3 + 0];
    const float t1 = xt[(b * 1024 + m) * 3 + 1];
    const float t2 = xt[(b * 1024 + m) * 3 + 2];

    const float* __restrict__ xab = xa   + (size_t)b * 1024 * 3 + nh * 512 * 3;
    const float* __restrict__ fb  = feat + (size_t)b * 1024 * 15 + nh * 512 * 15;

    float acc[15];
    #pragma unroll
    for (int kc = 0; kc < 15; ++kc) acc[kc] = 0.0f;

    if (uni) {
        const float c0 = coef[0], c1 = coef[1], c2 = coef[2];
        #pragma unroll 2
        for (int i = 0; i < 16; ++i) {
            const int n = i * 32 + ns;              // lane-consecutive n
            const float* __restrict__ f = fb + n * 15;
            const f4 fA = *(const f4*)(f);          // kc 0..3
            const f4 fB = *(const f4*)(f + 4);      // kc 4..7
            const f4 fC = *(const f4*)(f + 8);      // kc 8..11
            const f3 fD = *(const f3*)(f + 12);     // kc 12..14
            const f3 a  = *(const f3*)(xab + n * 3);
            float d0 = a.x - t0; d0 *= d0;
            float d1 = a.y - t1; d1 *= d1;
            float d2 = a.z - t2; d2 *= d2;
            const float w0 = __builtin_amdgcn_exp2f(d0 * c0);
            const float w1 = __builtin_amdgcn_exp2f(d1 * c1);
            const float w2 = __builtin_amdgcn_exp2f(d2 * c2);
            acc[0]  += w0 * fA.x;  acc[1]  += w1 * fA.y;  acc[2]  += w2 * fA.z;
            acc[3]  += w0 * fA.w;  acc[4]  += w1 * fB.x;  acc[5]  += w2 * fB.y;
            acc[6]  += w0 * fB.z;  acc[7]  += w1 * fB.w;  acc[8]  += w2 * fC.x;
            acc[9]  += w0 * fC.y;  acc[10] += w1 * fC.z;  acc[11] += w2 * fC.w;
            acc[12] += w0 * fD.x;  acc[13] += w1 * fD.y;  acc[14] += w2 * fD.z;
        }
    } else {
        // General path: 15 exps per n (correct for arbitrary log_std).
        for (int i = 0; i < 16; ++i) {
            const int n = i * 32 + ns;
            const float* __restrict__ f = fb + n * 15;
            float fv[15];
            *(f4*)(fv)     = *(const f4*)(f);
            *(f4*)(fv + 4) = *(const f4*)(f + 4);
            *(f4*)(fv + 8) = *(const f4*)(f + 8);
            *(f3*)(fv +12) = *(const f3*)(f + 12);
            const f3 a = *(const f3*)(xab + n * 3);
            float dd[3];
            dd[0] = a.x - t0; dd[0] *= dd[0];
            dd[1] = a.y - t1; dd[1] *= dd[1];
            dd[2] = a.z - t2; dd[2] *= dd[2];
            #pragma unroll
            for (int k = 0; k < 5; ++k)
                #pragma unroll
                for (int c = 0; c < 3; ++c)
                    acc[k * 3 + c] +=
                        __builtin_amdgcn_exp2f(dd[c] * coef[k * 3 + c]) * fv[k * 3 + c];
        }
    }

    // Stash partials: layout [mi][ns][15] (tid = mi*32+ns).
    #pragma unroll
    for (int kc = 0; kc < 15; ++kc) lds[tid * 15 + kc] = acc[kc];
    __syncthreads();

    // 120 outputs per block (8 m x 15 kc); thread t sums 32 ns-partials,
    // then atomically combines the two n-halves? No: halves write disjoint?
    // They don't - both halves cover the same (m,kc). Combine via atomicAdd
    // would reintroduce traffic; instead each half writes its own region of
    // d_ws? Simpler: only 2 halves -> use atomicAdd on L2 (2-way contention,
    // 245760 atomics total - cheap) ... but plain stores are free when nh
    // splits are merged here instead: NOT possible across blocks. Use 2-way
    // atomic: measured round-1 cost was from 32-way contention x 3.9M ops;
    // here 122880 adds x 2 = tolerable. (out is zeroed in kernel_launch.)
    if (tid < 120) {
        const int mi2 = tid / 15;
        const int kc  = tid - mi2 * 15;
        float s = 0.0f;
        #pragma unroll
        for (int ns2 = 0; ns2 < 32; ++ns2)
            s += lds[(mi2 * 32 + ns2) * 15 + kc];
        atomicAdd(&out[((size_t)b * 1024 + mt * 8 + mi2) * 15 + kc], s);
    }
}

extern "C" void kernel_launch(void* const* d_in, const int* in_sizes, int n_in,
                              void* d_out, int out_size, void* d_ws, size_t ws_size,
                              hipStream_t stream) {
    const float* xa      = (const float*)d_in[0];  // (8,1024,1,3)
    const float* feat    = (const float*)d_in[1];  // (8,1024,5,3)
    const float* xt      = (const float*)d_in[2];  // (8,1024,1,3)
    const float* log_std = (const float*)d_in[3];  // (1,5,3)
    float* out = (float*)d_out;                    // (8,1024,5,3)

    hipMemsetAsync(out, 0, (size_t)out_size * sizeof(float), stream);
    icgp_rbf_kernel<<<dim3(2048), dim3(256), 0, stream>>>(xa, feat, xt, log_std, out);
}

// Round 4
// 72.325 us; speedup vs baseline: 1.3300x; 1.3300x over previous
//
#include <hip/hip_runtime.h>

#define EPS_F 1e-6f
#define LOG2E 1.4426950408889634f

typedef float f4a __attribute__((ext_vector_type(4), aligned(16)));

// Force a (known-uniform) float into an SGPR.
__device__ __forceinline__ float rfl(float x) {
    return __builtin_bit_cast(float, __builtin_amdgcn_readfirstlane(__builtin_bit_cast(int, x)));
}

// Kernel 1: partial sums over 128-wide n-chunks.
// grid = 1024 blocks = B(8) x m-tiles(16) x n-chunks(8); block = 256 thr = 4 waves.
// lane <-> m (64 m's per block, same set for all 4 waves); wave w sums n in
// [chunk*128 + w*32, +32). feat/xa rows staged in LDS (rows padded to 16/4
// floats -> 16B-aligned b128 reads); inner-loop ds_reads are all-lanes-same-
// address -> HW broadcast, no per-lane VMEM, offsets are immediates.
// 4-wave partials combined in LDS; 8 n-chunk slices stored plain to d_ws.
__global__ __launch_bounds__(256, 4) void icgp_partial_kernel(
    const float* __restrict__ xa,       // (B, 1024, 1, 3)
    const float* __restrict__ feat,     // (B, 1024, 5, 3)
    const float* __restrict__ xt,       // (B, 1024, 1, 3)
    const float* __restrict__ log_std,  // (1, 5, 3)
    float* __restrict__ pws)            // (8, B*1024*15) partials
{
    // staging: sfeat = lds[0..2047] (128 rows x 16), sxa = lds[2048..2559]
    // (128 rows x 4); epilogue reuses lds[0..3839] (256 x 15).
    __shared__ float lds[3840];         // 15360 B

    const int bid  = blockIdx.x;
    const int nsb  = bid & 7;           // n-chunk
    const int mt   = (bid >> 3) & 15;   // m-tile (64 m's)
    const int b    = bid >> 7;
    const int tid  = threadIdx.x;
    const int wv   = tid >> 6;          // 0..3
    const int lane = tid & 63;
    const int m    = mt * 64 + lane;
    const int n0   = nsb * 128;

    // ---- stage feat (1920 floats) and xa (384 floats) into padded LDS ----
    const float* __restrict__ fg = feat + ((size_t)b * 1024 + n0) * 15; // 16B-aligned
    for (int j = tid; j < 480; j += 256) {
        const f4a v = *(const f4a*)(fg + j * 4);
        #pragma unroll
        for (int e = 0; e < 4; ++e) {
            const int g = j * 4 + e;
            const int r = g / 15, c = g - r * 15;
            lds[r * 16 + c] = v[e];
        }
    }
    const float* __restrict__ ag = xa + ((size_t)b * 1024 + n0) * 3;    // 16B-aligned
    if (tid < 96) {
        const f4a v = *(const f4a*)(ag + tid * 4);
        #pragma unroll
        for (int e = 0; e < 4; ++e) {
            const int g = tid * 4 + e;
            const int r = g / 3, c = g - r * 3;
            lds[2048 + r * 4 + c] = v[e];
        }
    }

    // ---- coefficients: wt = exp2(coef*(xa-xt)^2), coef = -0.5*log2e/std^2 ----
    float coef[15];
    #pragma unroll
    for (int kc = 0; kc < 15; ++kc) {
        const float s = __expf(log_std[kc]) + EPS_F;
        coef[kc] = rfl(-0.5f * LOG2E / (s * s));
    }
    bool uni = true;
    #pragma unroll
    for (int k = 1; k < 5; ++k)
        #pragma unroll
        for (int c = 0; c < 3; ++c)
            uni = uni && (coef[k * 3 + c] == coef[c]);

    const float t0 = xt[(b * 1024 + m) * 3 + 0];
    const float t1 = xt[(b * 1024 + m) * 3 + 1];
    const float t2 = xt[(b * 1024 + m) * 3 + 2];

    __syncthreads();

    float acc[15];
    #pragma unroll
    for (int kc = 0; kc < 15; ++kc) acc[kc] = 0.0f;

    const int rb = wv * 32;             // this wave's first LDS row

    if (uni) {
        const float c0 = coef[0], c1 = coef[1], c2 = coef[2];
        #pragma unroll 8
        for (int i = 0; i < 32; ++i) {
            const float* __restrict__ row = &lds[(rb + i) * 16];
            const f4a fA = *(const f4a*)(row);        // kc 0..3
            const f4a fB = *(const f4a*)(row + 4);    // kc 4..7
            const f4a fC = *(const f4a*)(row + 8);    // kc 8..11
            const f4a fD = *(const f4a*)(row + 12);   // kc 12..14 (+pad)
            const f4a av = *(const f4a*)(&lds[2048 + (rb + i) * 4]); // xa (+pad)
            float d0 = av.x - t0; d0 *= d0;
            float d1 = av.y - t1; d1 *= d1;
            float d2 = av.z - t2; d2 *= d2;
            const float w0 = __builtin_amdgcn_exp2f(d0 * c0);
            const float w1 = __builtin_amdgcn_exp2f(d1 * c1);
            const float w2 = __builtin_amdgcn_exp2f(d2 * c2);
            acc[0]  += w0 * fA.x;  acc[1]  += w1 * fA.y;  acc[2]  += w2 * fA.z;
            acc[3]  += w0 * fA.w;  acc[4]  += w1 * fB.x;  acc[5]  += w2 * fB.y;
            acc[6]  += w0 * fB.z;  acc[7]  += w1 * fB.w;  acc[8]  += w2 * fC.x;
            acc[9]  += w0 * fC.y;  acc[10] += w1 * fC.z;  acc[11] += w2 * fC.w;
            acc[12] += w0 * fD.x;  acc[13] += w1 * fD.y;  acc[14] += w2 * fD.z;
        }
    } else {
        // General path: 15 exps per n (correct for arbitrary log_std).
        for (int i = 0; i < 32; ++i) {
            const float* __restrict__ row = &lds[(rb + i) * 16];
            float fv[16];
            *(f4a*)(fv)      = *(const f4a*)(row);
            *(f4a*)(fv + 4)  = *(const f4a*)(row + 4);
            *(f4a*)(fv + 8)  = *(const f4a*)(row + 8);
            *(f4a*)(fv + 12) = *(const f4a*)(row + 12);
            const f4a av = *(const f4a*)(&lds[2048 + (rb + i) * 4]);
            float dd[3];
            dd[0] = av.x - t0; dd[0] *= dd[0];
            dd[1] = av.y - t1; dd[1] *= dd[1];
            dd[2] = av.z - t2; dd[2] *= dd[2];
            #pragma unroll
            for (int k = 0; k < 5; ++k)
                #pragma unroll
                for (int c = 0; c < 3; ++c)
                    acc[k * 3 + c] +=
                        __builtin_amdgcn_exp2f(dd[c] * coef[k * 3 + c]) * fv[k * 3 + c];
        }
    }

    // ---- in-block combine of the 4 wave-partials, plain store to pws ----
    __syncthreads();                    // all waves done reading staging
    #pragma unroll
    for (int kc = 0; kc < 15; ++kc) lds[tid * 15 + kc] = acc[kc];
    __syncthreads();

    float* __restrict__ pb = pws + (size_t)nsb * 122880
                                 + ((size_t)b * 1024 + mt * 64) * 15;
    #pragma unroll
    for (int j = 0; j < 4; ++j) {
        const int oidx = j * 256 + tid;         // 0..959
        if (oidx < 960) {
            const int mm = oidx / 15, kc = oidx - mm * 15;
            float s = 0.0f;
            #pragma unroll
            for (int w = 0; w < 4; ++w)
                s += lds[(w * 64 + mm) * 15 + kc];
            pb[oidx] = s;                        // coalesced
        }
    }
}

// Kernel 2: sum the 8 n-chunk slices. 122880 outputs, fully coalesced.
__global__ __launch_bounds__(256) void icgp_reduce_kernel(
    const float* __restrict__ pws, float* __restrict__ out)
{
    const int idx = blockIdx.x * 256 + threadIdx.x;   // < 122880
    float s = 0.0f;
    #pragma unroll
    for (int ns = 0; ns < 8; ++ns)
        s += pws[(size_t)ns * 122880 + idx];
    out[idx] = s;
}

extern "C" void kernel_launch(void* const* d_in, const int* in_sizes, int n_in,
                              void* d_out, int out_size, void* d_ws, size_t ws_size,
                              hipStream_t stream) {
    const float* xa      = (const float*)d_in[0];  // (8,1024,1,3)
    const float* feat    = (const float*)d_in[1];  // (8,1024,5,3)
    const float* xt      = (const float*)d_in[2];  // (8,1024,1,3)
    const float* log_std = (const float*)d_in[3];  // (1,5,3)
    float* out = (float*)d_out;                    // (8,1024,5,3)
    float* pws = (float*)d_ws;                     // 8 x 122880 floats = 3.93 MB

    icgp_partial_kernel<<<dim3(1024), dim3(256), 0, stream>>>(xa, feat, xt, log_std, pws);
    icgp_reduce_kernel<<<dim3(480), dim3(256), 0, stream>>>(pws, out);
}